// Round 28
// baseline (92.181 us; speedup 1.0000x reference)
//
#include <hip/hip_runtime.h>

typedef float    f32x4 __attribute__((ext_vector_type(4)));
typedef short    s16x8 __attribute__((ext_vector_type(8)));
typedef _Float16 f16x8 __attribute__((ext_vector_type(8)));
typedef _Float16 f16x4 __attribute__((ext_vector_type(4)));
typedef unsigned int   u32x4 __attribute__((ext_vector_type(4)));

// B=8, N=1024, F=1024, H=16, D=64

__device__ __forceinline__ unsigned short bf16rne(float f){
  unsigned u = __float_as_uint(f);
  return (unsigned short)((u + 0x7FFFu + ((u >> 16) & 1u)) >> 16);
}

// ---------------- prep: xbf | prepw (adjmask moved into gemm dispatch) --------
__global__ __launch_bounds__(256) void prep_kernel(const float* __restrict__ x,
    const float* __restrict__ W,
    unsigned short* __restrict__ xb, unsigned short* __restrict__ Wt)
{
  const int bid = blockIdx.x, tid = threadIdx.x;
  if (bid < 4096) {
    int idx = (bid * 256 + tid) * 8;
    f32x4 v0 = *reinterpret_cast<const f32x4*>(&x[idx]);
    f32x4 v1 = *reinterpret_cast<const f32x4*>(&x[idx + 4]);
    u32x4 o;
    o[0] = (unsigned)bf16rne(v0[0]) | ((unsigned)bf16rne(v0[1]) << 16);
    o[1] = (unsigned)bf16rne(v0[2]) | ((unsigned)bf16rne(v0[3]) << 16);
    o[2] = (unsigned)bf16rne(v1[0]) | ((unsigned)bf16rne(v1[1]) << 16);
    o[3] = (unsigned)bf16rne(v1[2]) | ((unsigned)bf16rne(v1[3]) << 16);
    *reinterpret_cast<u32x4*>(&xb[idx]) = o;
  } else {
    __shared__ float t[16][17];
    int rel = bid - 4096;
    int f0 = (rel & 63) * 16, d0 = ((rel >> 6) & 3) * 16, hh = rel >> 8;
    const int tx = tid & 15, ty = tid >> 4;
    t[ty][tx] = W[(size_t)hh * 65536 + (size_t)(f0 + ty) * 64 + (d0 + tx)];
    __syncthreads();
    float v = t[tx][ty];  // = W[hh][f0+tx][d0+ty]
    size_t o = (size_t)(hh * 64 + d0 + ty) * 1024 + (f0 + tx);
    Wt[o] = bf16rne(v);
  }
}

// ---------------- Wh = xb @ Wt^T (dbuf) | adjmask (grid-branched, hidden) -----
// gemm is latency-bound at 2 blocks/CU; adjmask blocks (lin>=512) run in the
// idle slots concurrently. maskb is consumed only by pv (after this kernel).
// Note: default lin%8 = m-tile%8 already gives A-panel XCD locality.
#define GSTAGE(BUF, K0) { \
  _Pragma("unroll") \
  for (int r = 0; r < 2; ++r) { \
    int flat = r * 256 + tid; int row = flat >> 2; int o8 = (flat & 3) << 3; \
    *reinterpret_cast<u32x4*>(&Ah[BUF][row * 40 + o8]) = \
        *reinterpret_cast<const u32x4*>(&xb[(size_t)(m0 + row) * 1024 + (K0) + o8]); \
  } \
  _Pragma("unroll") \
  for (int r = 0; r < 2; ++r) { \
    int flat = r * 256 + tid; int row = flat >> 2; int o8 = (flat & 3) << 3; \
    *reinterpret_cast<u32x4*>(&Bh[BUF][row * 40 + o8]) = \
        *reinterpret_cast<const u32x4*>(&Btg[(size_t)(n0 + row) * 1024 + (K0) + o8]); \
  } }

__global__ __launch_bounds__(256, 3) void gemm_kernel(const unsigned short* __restrict__ xb,
    const unsigned short* __restrict__ Btg,
    const float* __restrict__ a1, const float* __restrict__ a2,
    const int* __restrict__ adj, unsigned* __restrict__ maskb,
    _Float16* __restrict__ WhT, float* __restrict__ f1, float* __restrict__ f2)
{
  __shared__ unsigned short Ah[2][128 * 40], Bh[2][128 * 40];
  const int tid = threadIdx.x;
  const int lin = blockIdx.x;
  if (lin >= 512) {
    // adjmask: 4096 waves over 131072 rows
    const int lane = tid & 63;
    int gw = ((lin - 512) * 256 + tid) >> 6;
    for (int s = gw; s < 131072; s += 4096) {
      int a = adj[(size_t)s * 64 + lane];
      unsigned long long m = __ballot(a > 0);
      if (lane == 0) {
        maskb[s * 2]     = (unsigned)m;
        maskb[s * 2 + 1] = (unsigned)(m >> 32);
      }
    }
    return;
  }
  const int lane = tid & 63, wave = tid >> 6;
  const int m0 = (lin & 63) * 128, n0 = (lin >> 6) * 128;
  const int wm = (wave & 1) * 64, wn = (wave >> 1) * 64;
  const int rA = lane & 15, kg = lane >> 4;

  f32x4 acc[4][4] = {};

  GSTAGE(0, 0);
  __syncthreads();
  int cur = 0;
  for (int k0 = 0; k0 < 1024; k0 += 32) {
    if (k0 + 32 < 1024) { GSTAGE(cur ^ 1, k0 + 32); }

    s16x8 ah[4], bh[4];
#pragma unroll
    for (int i = 0; i < 4; ++i)
      ah[i] = *reinterpret_cast<const s16x8*>(&Ah[cur][(wm + i * 16 + rA) * 40 + kg * 8]);
#pragma unroll
    for (int j = 0; j < 4; ++j)
      bh[j] = *reinterpret_cast<const s16x8*>(&Bh[cur][(wn + j * 16 + rA) * 40 + kg * 8]);
#pragma unroll
    for (int i = 0; i < 4; ++i)
#pragma unroll
      for (int j = 0; j < 4; ++j)
        acc[i][j] = __builtin_amdgcn_mfma_f32_16x16x32_bf16(ah[i], bh[j], acc[i][j], 0, 0, 0);
    __syncthreads();
    cur ^= 1;
  }

  // epilogue 1: WhT f16 [(bh*64+d)*1024 + n-within-batch]
#pragma unroll
  for (int i = 0; i < 4; ++i) {
    int gm0 = m0 + wm + i * 16 + kg * 4;  // 4 consecutive rows
#pragma unroll
    for (int j = 0; j < 4; ++j) {
      int gn = n0 + wn + j * 16 + rA;
      int bb = gm0 >> 10, nn = gm0 & 1023;
      int hh = gn >> 6,  dd = gn & 63;
      f16x4 hv;
#pragma unroll
      for (int jj = 0; jj < 4; ++jj) hv[jj] = (_Float16)acc[i][j][jj];
      *reinterpret_cast<f16x4*>(&WhT[((size_t)((bb * 16 + hh) * 64 + dd) << 10) + nn]) = hv;
    }
  }

  // epilogue 2: fused f1/f2 (this wave's 64 cols = one complete head)
  const int hw = (n0 + wn) >> 6;        // absolute head 0..15
  float a1v[4], a2v[4];
#pragma unroll
  for (int j = 0; j < 4; ++j) {
    int d = j * 16 + rA;
    a1v[j] = a1[hw * 64 + d];
    a2v[j] = a2[hw * 64 + d];
  }
#pragma unroll
  for (int i = 0; i < 4; ++i) {
#pragma unroll
    for (int jj = 0; jj < 4; ++jj) {
      float s1 = 0.f, s2 = 0.f;
#pragma unroll
      for (int j = 0; j < 4; ++j) {
        float v = acc[i][j][jj];
        s1 += v * a1v[j];
        s2 += v * a2v[j];
      }
#pragma unroll
      for (int off = 1; off < 16; off <<= 1) {
        s1 += __shfl_xor(s1, off);
        s2 += __shfl_xor(s2, off);
      }
      if (rA == 0) {
        int gm = m0 + wm + i * 16 + kg * 4 + jj;
        int bb = gm >> 10, nn = gm & 1023;
        size_t o = (size_t)(bb * 16 + hw) * 1024 + nn;
        f1[o] = s1;
        f2[o] = s2;
      }
    }
  }
}

// ---------------- PV: R27 (scalar max + pkrtz, dbuf, lut, ones-MFMA, XCD) -----
#define PSTAGE(BUF, M0) { \
  _Pragma("unroll") \
  for (int r = 0; r < 2; ++r) { \
    int flat = r * 256 + tid; int d = flat >> 3; int o = (flat & 7) << 3; \
    *reinterpret_cast<u32x4*>(&Bsh[BUF][d * 72 + o]) = \
        *reinterpret_cast<const u32x4*>(&whtb[(size_t)d * 1024 + (M0) + o]); \
  } }

__global__ __launch_bounds__(256, 4) void pv_kernel(const _Float16* __restrict__ WhT,
    const float* __restrict__ f1, const float* __restrict__ f2,
    const unsigned* __restrict__ maskb, float* __restrict__ y)
{
  const int tid = threadIdx.x, lane = tid & 63, wave = tid >> 6;
  const int lin = blockIdx.x;
  const int bh = ((lin >> 6) << 3) + (lin & 7);   // bh&7 = lin&7 -> xcd locality
  const int rb = (lin >> 3) & 7;
  const int b = bh >> 4, h = bh & 15;
  const int n0 = rb * 128;
  const _Float16* whtb = WhT + ((size_t)bh << 16);  // 64*1024 per (b,h)

  __shared__ _Float16 Bsh[2][64 * 72];
  __shared__ float Cs[1024], Ds[1024];
  __shared__ float smx[4];
  __shared__ unsigned long long lutm[16];

  const float K = 1.44269504f;

  // phase 0: compute C=2^f2', D=2^0.2f2' (+ block max of f2'), lut
  float pmax;
  {
    f32x4 fv = *reinterpret_cast<const f32x4*>(&f2[(size_t)bh * 1024 + tid * 4]);
    f32x4 sv, cv, dv;
#pragma unroll
    for (int e = 0; e < 4; ++e) {
      sv[e] = fv[e] * K;
      cv[e] = __builtin_amdgcn_exp2f(sv[e]);
      dv[e] = __builtin_amdgcn_exp2f(0.2f * sv[e]);
    }
    *reinterpret_cast<f32x4*>(&Cs[tid * 4]) = cv;
    *reinterpret_cast<f32x4*>(&Ds[tid * 4]) = dv;
    pmax = fmaxf(fmaxf(sv[0], sv[1]), fmaxf(sv[2], sv[3]));
  }
#pragma unroll
  for (int off = 32; off; off >>= 1) pmax = fmaxf(pmax, __shfl_xor(pmax, off));
  if (lane == 0) smx[wave] = pmax;
  if (tid < 16) {
    unsigned lo = ((tid & 1) ? 0xFFFFu : 0u) | ((tid & 2) ? 0xFFFF0000u : 0u);
    unsigned hi = ((tid & 4) ? 0xFFFFu : 0u) | ((tid & 8) ? 0xFFFF0000u : 0u);
    lutm[tid] = ((unsigned long long)hi << 32) | lo;
  }
  __syncthreads();

  const float m2s = fmaxf(fmaxf(smx[0], smx[1]), fmaxf(smx[2], smx[3]));

  const int rA = lane & 15, kg = lane >> 4;
  const int wrow = wave * 32;
  f32x4 acc[2][4] = {};
  f32x4 dacc[2] = {};
  int   rloc[2];
  float At[2], Bt[2];
  const unsigned* mrow[2];
#pragma unroll
  for (int t = 0; t < 2; ++t) {
    rloc[t] = wrow + t * 16 + rA;
    float f1p = f1[(size_t)bh * 1024 + n0 + rloc[t]] * K;
    float sf = f1p + m2s;
    float Mp = fmaxf(sf, 0.2f * sf);
    At[t] = __builtin_amdgcn_exp2f(f1p - Mp);
    Bt[t] = __builtin_amdgcn_exp2f(0.2f * f1p - Mp);
    mrow[t] = maskb + ((size_t)(b << 10) + n0 + rloc[t]) * 32;
  }
  f16x8 ones;
#pragma unroll
  for (int e = 0; e < 8; ++e) ones[e] = (_Float16)1.0f;

  uint2 mwcur[2], mwnext[2];
#pragma unroll
  for (int t = 0; t < 2; ++t)
    mwcur[t] = *reinterpret_cast<const uint2*>(&mrow[t][0]);
  PSTAGE(0, 0);
  __syncthreads();
  int cur = 0;

  for (int m0 = 0; m0 < 1024; m0 += 64) {
    if (m0 + 64 < 1024) {
      PSTAGE(cur ^ 1, m0 + 64);
#pragma unroll
      for (int t = 0; t < 2; ++t)
        mwnext[t] = *reinterpret_cast<const uint2*>(&mrow[t][(m0 + 64) >> 5]);
    }
    // hoist all C/D loads for both ks (8x ds_read_b128, latencies overlap)
    f32x4 cd[2][4];
#pragma unroll
    for (int ks = 0; ks < 2; ++ks) {
      const int kc = m0 + ks * 32 + kg * 8;
      cd[ks][0] = *reinterpret_cast<const f32x4*>(&Cs[kc]);
      cd[ks][1] = *reinterpret_cast<const f32x4*>(&Cs[kc + 4]);
      cd[ks][2] = *reinterpret_cast<const f32x4*>(&Ds[kc]);
      cd[ks][3] = *reinterpret_cast<const f32x4*>(&Ds[kc + 4]);
    }
#pragma unroll
    for (int ks = 0; ks < 2; ++ks) {
      f16x8 pa[2];
#pragma unroll
      for (int t = 0; t < 2; ++t) {
        unsigned mw = (&mwcur[t].x)[ks] >> (kg * 8);
        float pv_[8];
#pragma unroll
        for (int jj = 0; jj < 8; ++jj) {
          float C = (jj < 4) ? cd[ks][0][jj] : cd[ks][1][jj - 4];
          float D = (jj < 4) ? cd[ks][2][jj] : cd[ks][3][jj - 4];
          pv_[jj] = fmaxf(At[t] * C, Bt[t] * D);
        }
        u32x4 pw;
        pw[0] = __builtin_bit_cast(unsigned, __builtin_amdgcn_cvt_pkrtz(pv_[0], pv_[1]));
        pw[1] = __builtin_bit_cast(unsigned, __builtin_amdgcn_cvt_pkrtz(pv_[2], pv_[3]));
        pw[2] = __builtin_bit_cast(unsigned, __builtin_amdgcn_cvt_pkrtz(pv_[4], pv_[5]));
        pw[3] = __builtin_bit_cast(unsigned, __builtin_amdgcn_cvt_pkrtz(pv_[6], pv_[7]));
        unsigned long long mq0 = lutm[mw & 15u];
        unsigned long long mq1 = lutm[(mw >> 4) & 15u];
        pw[0] &= (unsigned)mq0;  pw[1] &= (unsigned)(mq0 >> 32);
        pw[2] &= (unsigned)mq1;  pw[3] &= (unsigned)(mq1 >> 32);
        pa[t] = __builtin_bit_cast(f16x8, pw);
        dacc[t] = __builtin_amdgcn_mfma_f32_16x16x32_f16(pa[t], ones, dacc[t], 0, 0, 0);
      }
#pragma unroll
      for (int j = 0; j < 4; ++j) {
        f16x8 bf = *reinterpret_cast<const f16x8*>(&Bsh[cur][(j * 16 + rA) * 72 + ks * 32 + kg * 8]);
        acc[0][j] = __builtin_amdgcn_mfma_f32_16x16x32_f16(pa[0], bf, acc[0][j], 0, 0, 0);
        acc[1][j] = __builtin_amdgcn_mfma_f32_16x16x32_f16(pa[1], bf, acc[1][j], 0, 0, 0);
      }
    }
    __syncthreads();
    cur ^= 1;
#pragma unroll
    for (int t = 0; t < 2; ++t) mwcur[t] = mwnext[t];
  }

  // epilogue: dacc[t] rows (t*16 + kg*4+jj) align with acc[t] rows
#pragma unroll
  for (int t = 0; t < 2; ++t) {
    f32x4 rd;
#pragma unroll
    for (int jj = 0; jj < 4; ++jj) rd[jj] = dacc[t][jj] > 0.f ? 1.0f / dacc[t][jj] : 0.f;
#pragma unroll
    for (int j = 0; j < 4; ++j) {
#pragma unroll
      for (int jj = 0; jj < 4; ++jj) {
        int row = wrow + t * 16 + kg * 4 + jj;
        int n = n0 + row, d = j * 16 + rA;
        y[(((size_t)b * 1024 + n) << 10) + h * 64 + d] = acc[t][j][jj] * rd[jj];
      }
    }
  }
}

extern "C" void kernel_launch(void* const* d_in, const int* in_sizes, int n_in,
                              void* d_out, int out_size, void* d_ws, size_t ws_size,
                              hipStream_t stream)
{
  const float* x  = (const float*)d_in[0];
  const int*   adj = (const int*)d_in[1];
  const float* W  = (const float*)d_in[2];
  const float* a1 = (const float*)d_in[3];
  const float* a2 = (const float*)d_in[4];
  float* y = (float*)d_out;

  char* ws = (char*)d_ws;
  unsigned short* Wt = (unsigned short*)(ws);                       // 2 MB
  unsigned*       maskb = (unsigned*)(ws + ((size_t)2 << 20));      // 1 MB
  float* f1   = (float*)(ws + ((size_t)3 << 20));                   // 512 KB
  float* f2   = (float*)(ws + ((size_t)3 << 20) + ((size_t)512 << 10));
  _Float16* WhT = (_Float16*)(ws + ((size_t)4 << 20));              // 16 MB
  unsigned short* xb = (unsigned short*)(ws + ((size_t)20 << 20));  // 16 MB

  prep_kernel<<<8192, 256, 0, stream>>>(x, W, xb, Wt);
  gemm_kernel<<<1536, 256, 0, stream>>>(xb, Wt, a1, a2, adj, maskb, WhT, f1, f2);
  pv_kernel<<<1024, 256, 0, stream>>>(WhT, f1, f2, maskb, y);
}

// Round 29
// 88.790 us; speedup vs baseline: 1.0382x; 1.0382x over previous
//
#include <hip/hip_runtime.h>

typedef float    f32x4 __attribute__((ext_vector_type(4)));
typedef short    s16x8 __attribute__((ext_vector_type(8)));
typedef _Float16 f16x8 __attribute__((ext_vector_type(8)));
typedef _Float16 f16x4 __attribute__((ext_vector_type(4)));
typedef unsigned int   u32x4 __attribute__((ext_vector_type(4)));

// B=8, N=1024, F=1024, H=16, D=64

__device__ __forceinline__ unsigned short bf16rne(float f){
  unsigned u = __float_as_uint(f);
  return (unsigned short)((u + 0x7FFFu + ((u >> 16) & 1u)) >> 16);
}

// ---------------- fused prep: adjmask | xbf | prepw (grid-branched) -----------
__global__ __launch_bounds__(256) void prep_kernel(const int* __restrict__ adj,
    const float* __restrict__ x, const float* __restrict__ W,
    unsigned* __restrict__ maskb, unsigned short* __restrict__ xb,
    unsigned short* __restrict__ Wt)
{
  const int bid = blockIdx.x, tid = threadIdx.x;
  if (bid < 1024) {
    const int lane = tid & 63;
    int gw = (bid * 256 + tid) >> 6;
    for (int s = gw; s < 131072; s += 4096) {
      int a = adj[(size_t)s * 64 + lane];
      unsigned long long m = __ballot(a > 0);
      if (lane == 0) {
        maskb[s * 2]     = (unsigned)m;
        maskb[s * 2 + 1] = (unsigned)(m >> 32);
      }
    }
  } else if (bid < 5120) {
    int idx = ((bid - 1024) * 256 + tid) * 8;
    f32x4 v0 = *reinterpret_cast<const f32x4*>(&x[idx]);
    f32x4 v1 = *reinterpret_cast<const f32x4*>(&x[idx + 4]);
    u32x4 o;
    o[0] = (unsigned)bf16rne(v0[0]) | ((unsigned)bf16rne(v0[1]) << 16);
    o[1] = (unsigned)bf16rne(v0[2]) | ((unsigned)bf16rne(v0[3]) << 16);
    o[2] = (unsigned)bf16rne(v1[0]) | ((unsigned)bf16rne(v1[1]) << 16);
    o[3] = (unsigned)bf16rne(v1[2]) | ((unsigned)bf16rne(v1[3]) << 16);
    *reinterpret_cast<u32x4*>(&xb[idx]) = o;
  } else {
    __shared__ float t[16][17];
    int rel = bid - 5120;
    int f0 = (rel & 63) * 16, d0 = ((rel >> 6) & 3) * 16, hh = rel >> 8;
    const int tx = tid & 15, ty = tid >> 4;
    t[ty][tx] = W[(size_t)hh * 65536 + (size_t)(f0 + ty) * 64 + (d0 + tx)];
    __syncthreads();
    float v = t[tx][ty];  // = W[hh][f0+tx][d0+ty]
    size_t o = (size_t)(hh * 64 + d0 + ty) * 1024 + (f0 + tx);
    Wt[o] = bf16rne(v);
  }
}

// ---------------- Wh = xb @ Wt^T — 128x128, dbuf, global_load_lds staging -----
// Async direct-to-LDS (guide m97: +67% on this exact pattern). LDS layout is
// LINEAR (stride 32 shorts = 64B/row): dest byte = flat*16 = wave_base + lane*16
// as required (wave-uniform base + lane*size). Padding dropped; ~8-way conflict
// on fragment ds_read_b128 accepted (small vs removing the VGPR round-trip).
#define GSTAGE(BUF, K0) { \
  _Pragma("unroll") \
  for (int r = 0; r < 2; ++r) { \
    int flat = r * 256 + tid; \
    int row = flat >> 2, o8 = (flat & 3) << 3; \
    __builtin_amdgcn_global_load_lds( \
        (const __attribute__((address_space(1))) unsigned*)&xb[(size_t)(m0 + row) * 1024 + (K0) + o8], \
        (__attribute__((address_space(3))) unsigned*)&Ah[BUF][(r * 256 + (wave << 6)) * 8], 16, 0, 0); \
    __builtin_amdgcn_global_load_lds( \
        (const __attribute__((address_space(1))) unsigned*)&Btg[(size_t)(n0 + row) * 1024 + (K0) + o8], \
        (__attribute__((address_space(3))) unsigned*)&Bh[BUF][(r * 256 + (wave << 6)) * 8], 16, 0, 0); \
  } }

__global__ __launch_bounds__(256, 3) void gemm_kernel(const unsigned short* __restrict__ xb,
    const unsigned short* __restrict__ Btg,
    const float* __restrict__ a1, const float* __restrict__ a2,
    _Float16* __restrict__ WhT, float* __restrict__ f1, float* __restrict__ f2)
{
  __shared__ unsigned short Ah[2][128 * 32], Bh[2][128 * 32];
  const int tid  = threadIdx.x;
  const int lane = tid & 63, wave = tid >> 6;
  const int m0 = blockIdx.x * 128, n0 = blockIdx.y * 128;
  const int wm = (wave & 1) * 64, wn = (wave >> 1) * 64;
  const int rA = lane & 15, kg = lane >> 4;

  f32x4 acc[4][4] = {};

  GSTAGE(0, 0);
  __syncthreads();
  int cur = 0;
  for (int k0 = 0; k0 < 1024; k0 += 32) {
    if (k0 + 32 < 1024) { GSTAGE(cur ^ 1, k0 + 32); }

    s16x8 ah[4], bh[4];
#pragma unroll
    for (int i = 0; i < 4; ++i)
      ah[i] = *reinterpret_cast<const s16x8*>(&Ah[cur][(wm + i * 16 + rA) * 32 + kg * 8]);
#pragma unroll
    for (int j = 0; j < 4; ++j)
      bh[j] = *reinterpret_cast<const s16x8*>(&Bh[cur][(wn + j * 16 + rA) * 32 + kg * 8]);
#pragma unroll
    for (int i = 0; i < 4; ++i)
#pragma unroll
      for (int j = 0; j < 4; ++j)
        acc[i][j] = __builtin_amdgcn_mfma_f32_16x16x32_bf16(ah[i], bh[j], acc[i][j], 0, 0, 0);
    __syncthreads();
    cur ^= 1;
  }

  // epilogue 1: WhT f16 [(bh*64+d)*1024 + n-within-batch]
#pragma unroll
  for (int i = 0; i < 4; ++i) {
    int gm0 = m0 + wm + i * 16 + kg * 4;  // 4 consecutive rows
#pragma unroll
    for (int j = 0; j < 4; ++j) {
      int gn = n0 + wn + j * 16 + rA;
      int bb = gm0 >> 10, nn = gm0 & 1023;
      int hh = gn >> 6,  dd = gn & 63;
      f16x4 hv;
#pragma unroll
      for (int jj = 0; jj < 4; ++jj) hv[jj] = (_Float16)acc[i][j][jj];
      *reinterpret_cast<f16x4*>(&WhT[((size_t)((bb * 16 + hh) * 64 + dd) << 10) + nn]) = hv;
    }
  }

  // epilogue 2: fused f1/f2 (this wave's 64 cols = one complete head)
  const int hw = (n0 + wn) >> 6;        // absolute head 0..15
  float a1v[4], a2v[4];
#pragma unroll
  for (int j = 0; j < 4; ++j) {
    int d = j * 16 + rA;
    a1v[j] = a1[hw * 64 + d];
    a2v[j] = a2[hw * 64 + d];
  }
#pragma unroll
  for (int i = 0; i < 4; ++i) {
#pragma unroll
    for (int jj = 0; jj < 4; ++jj) {
      float s1 = 0.f, s2 = 0.f;
#pragma unroll
      for (int j = 0; j < 4; ++j) {
        float v = acc[i][j][jj];
        s1 += v * a1v[j];
        s2 += v * a2v[j];
      }
#pragma unroll
      for (int off = 1; off < 16; off <<= 1) {
        s1 += __shfl_xor(s1, off);
        s2 += __shfl_xor(s2, off);
      }
      if (rA == 0) {
        int gm = m0 + wm + i * 16 + kg * 4 + jj;
        int bb = gm >> 10, nn = gm & 1023;
        size_t o = (size_t)(bb * 16 + hw) * 1024 + nn;
        f1[o] = s1;
        f2[o] = s2;
      }
    }
  }
}

// ---------------- PV: R27 (scalar max + pkrtz, dbuf, lut, ones-MFMA, XCD) -----
#define PSTAGE(BUF, M0) { \
  _Pragma("unroll") \
  for (int r = 0; r < 2; ++r) { \
    int flat = r * 256 + tid; int d = flat >> 3; int o = (flat & 7) << 3; \
    *reinterpret_cast<u32x4*>(&Bsh[BUF][d * 72 + o]) = \
        *reinterpret_cast<const u32x4*>(&whtb[(size_t)d * 1024 + (M0) + o]); \
  } }

__global__ __launch_bounds__(256, 4) void pv_kernel(const _Float16* __restrict__ WhT,
    const float* __restrict__ f1, const float* __restrict__ f2,
    const unsigned* __restrict__ maskb, float* __restrict__ y)
{
  const int tid = threadIdx.x, lane = tid & 63, wave = tid >> 6;
  const int lin = blockIdx.x;
  const int bh = ((lin >> 6) << 3) + (lin & 7);   // bh&7 = lin&7 -> xcd locality
  const int rb = (lin >> 3) & 7;
  const int b = bh >> 4, h = bh & 15;
  const int n0 = rb * 128;
  const _Float16* whtb = WhT + ((size_t)bh << 16);  // 64*1024 per (b,h)

  __shared__ _Float16 Bsh[2][64 * 72];
  __shared__ float Cs[1024], Ds[1024];
  __shared__ float smx[4];
  __shared__ unsigned long long lutm[16];

  const float K = 1.44269504f;

  // phase 0: compute C=2^f2', D=2^0.2f2' (+ block max of f2'), lut
  float pmax;
  {
    f32x4 fv = *reinterpret_cast<const f32x4*>(&f2[(size_t)bh * 1024 + tid * 4]);
    f32x4 sv, cv, dv;
#pragma unroll
    for (int e = 0; e < 4; ++e) {
      sv[e] = fv[e] * K;
      cv[e] = __builtin_amdgcn_exp2f(sv[e]);
      dv[e] = __builtin_amdgcn_exp2f(0.2f * sv[e]);
    }
    *reinterpret_cast<f32x4*>(&Cs[tid * 4]) = cv;
    *reinterpret_cast<f32x4*>(&Ds[tid * 4]) = dv;
    pmax = fmaxf(fmaxf(sv[0], sv[1]), fmaxf(sv[2], sv[3]));
  }
#pragma unroll
  for (int off = 32; off; off >>= 1) pmax = fmaxf(pmax, __shfl_xor(pmax, off));
  if (lane == 0) smx[wave] = pmax;
  if (tid < 16) {
    unsigned lo = ((tid & 1) ? 0xFFFFu : 0u) | ((tid & 2) ? 0xFFFF0000u : 0u);
    unsigned hi = ((tid & 4) ? 0xFFFFu : 0u) | ((tid & 8) ? 0xFFFF0000u : 0u);
    lutm[tid] = ((unsigned long long)hi << 32) | lo;
  }
  __syncthreads();

  const float m2s = fmaxf(fmaxf(smx[0], smx[1]), fmaxf(smx[2], smx[3]));

  const int rA = lane & 15, kg = lane >> 4;
  const int wrow = wave * 32;
  f32x4 acc[2][4] = {};
  f32x4 dacc[2] = {};
  int   rloc[2];
  float At[2], Bt[2];
  const unsigned* mrow[2];
#pragma unroll
  for (int t = 0; t < 2; ++t) {
    rloc[t] = wrow + t * 16 + rA;
    float f1p = f1[(size_t)bh * 1024 + n0 + rloc[t]] * K;
    float sf = f1p + m2s;
    float Mp = fmaxf(sf, 0.2f * sf);
    At[t] = __builtin_amdgcn_exp2f(f1p - Mp);
    Bt[t] = __builtin_amdgcn_exp2f(0.2f * f1p - Mp);
    mrow[t] = maskb + ((size_t)(b << 10) + n0 + rloc[t]) * 32;
  }
  f16x8 ones;
#pragma unroll
  for (int e = 0; e < 8; ++e) ones[e] = (_Float16)1.0f;

  uint2 mwcur[2], mwnext[2];
#pragma unroll
  for (int t = 0; t < 2; ++t)
    mwcur[t] = *reinterpret_cast<const uint2*>(&mrow[t][0]);
  PSTAGE(0, 0);
  __syncthreads();
  int cur = 0;

  for (int m0 = 0; m0 < 1024; m0 += 64) {
    if (m0 + 64 < 1024) {
      PSTAGE(cur ^ 1, m0 + 64);
#pragma unroll
      for (int t = 0; t < 2; ++t)
        mwnext[t] = *reinterpret_cast<const uint2*>(&mrow[t][(m0 + 64) >> 5]);
    }
    // hoist all C/D loads for both ks (8x ds_read_b128, latencies overlap)
    f32x4 cd[2][4];
#pragma unroll
    for (int ks = 0; ks < 2; ++ks) {
      const int kc = m0 + ks * 32 + kg * 8;
      cd[ks][0] = *reinterpret_cast<const f32x4*>(&Cs[kc]);
      cd[ks][1] = *reinterpret_cast<const f32x4*>(&Cs[kc + 4]);
      cd[ks][2] = *reinterpret_cast<const f32x4*>(&Ds[kc]);
      cd[ks][3] = *reinterpret_cast<const f32x4*>(&Ds[kc + 4]);
    }
#pragma unroll
    for (int ks = 0; ks < 2; ++ks) {
      f16x8 pa[2];
#pragma unroll
      for (int t = 0; t < 2; ++t) {
        unsigned mw = (&mwcur[t].x)[ks] >> (kg * 8);
        float pv_[8];
#pragma unroll
        for (int jj = 0; jj < 8; ++jj) {
          float C = (jj < 4) ? cd[ks][0][jj] : cd[ks][1][jj - 4];
          float D = (jj < 4) ? cd[ks][2][jj] : cd[ks][3][jj - 4];
          pv_[jj] = fmaxf(At[t] * C, Bt[t] * D);
        }
        u32x4 pw;
        pw[0] = __builtin_bit_cast(unsigned, __builtin_amdgcn_cvt_pkrtz(pv_[0], pv_[1]));
        pw[1] = __builtin_bit_cast(unsigned, __builtin_amdgcn_cvt_pkrtz(pv_[2], pv_[3]));
        pw[2] = __builtin_bit_cast(unsigned, __builtin_amdgcn_cvt_pkrtz(pv_[4], pv_[5]));
        pw[3] = __builtin_bit_cast(unsigned, __builtin_amdgcn_cvt_pkrtz(pv_[6], pv_[7]));
        unsigned long long mq0 = lutm[mw & 15u];
        unsigned long long mq1 = lutm[(mw >> 4) & 15u];
        pw[0] &= (unsigned)mq0;  pw[1] &= (unsigned)(mq0 >> 32);
        pw[2] &= (unsigned)mq1;  pw[3] &= (unsigned)(mq1 >> 32);
        pa[t] = __builtin_bit_cast(f16x8, pw);
        dacc[t] = __builtin_amdgcn_mfma_f32_16x16x32_f16(pa[t], ones, dacc[t], 0, 0, 0);
      }
#pragma unroll
      for (int j = 0; j < 4; ++j) {
        f16x8 bf = *reinterpret_cast<const f16x8*>(&Bsh[cur][(j * 16 + rA) * 72 + ks * 32 + kg * 8]);
        acc[0][j] = __builtin_amdgcn_mfma_f32_16x16x32_f16(pa[0], bf, acc[0][j], 0, 0, 0);
        acc[1][j] = __builtin_amdgcn_mfma_f32_16x16x32_f16(pa[1], bf, acc[1][j], 0, 0, 0);
      }
    }
    __syncthreads();
    cur ^= 1;
#pragma unroll
    for (int t = 0; t < 2; ++t) mwcur[t] = mwnext[t];
  }

  // epilogue: dacc[t] rows (t*16 + kg*4+jj) align with acc[t] rows
#pragma unroll
  for (int t = 0; t < 2; ++t) {
    f32x4 rd;
#pragma unroll
    for (int jj = 0; jj < 4; ++jj) rd[jj] = dacc[t][jj] > 0.f ? 1.0f / dacc[t][jj] : 0.f;
#pragma unroll
    for (int j = 0; j < 4; ++j) {
#pragma unroll
      for (int jj = 0; jj < 4; ++jj) {
        int row = wrow + t * 16 + kg * 4 + jj;
        int n = n0 + row, d = j * 16 + rA;
        y[(((size_t)b * 1024 + n) << 10) + h * 64 + d] = acc[t][j][jj] * rd[jj];
      }
    }
  }
}

extern "C" void kernel_launch(void* const* d_in, const int* in_sizes, int n_in,
                              void* d_out, int out_size, void* d_ws, size_t ws_size,
                              hipStream_t stream)
{
  const float* x  = (const float*)d_in[0];
  const int*   adj = (const int*)d_in[1];
  const float* W  = (const float*)d_in[2];
  const float* a1 = (const float*)d_in[3];
  const float* a2 = (const float*)d_in[4];
  float* y = (float*)d_out;

  char* ws = (char*)d_ws;
  unsigned short* Wt = (unsigned short*)(ws);                       // 2 MB
  unsigned*       maskb = (unsigned*)(ws + ((size_t)2 << 20));      // 1 MB
  float* f1   = (float*)(ws + ((size_t)3 << 20));                   // 512 KB
  float* f2   = (float*)(ws + ((size_t)3 << 20) + ((size_t)512 << 10));
  _Float16* WhT = (_Float16*)(ws + ((size_t)4 << 20));              // 16 MB
  unsigned short* xb = (unsigned short*)(ws + ((size_t)20 << 20));  // 16 MB

  prep_kernel<<<9216, 256, 0, stream>>>(adj, x, W, maskb, xb, Wt);
  gemm_kernel<<<dim3(64, 8), 256, 0, stream>>>(xb, Wt, a1, a2, WhT, f1, f2);
  pv_kernel<<<1024, 256, 0, stream>>>(WhT, f1, f2, maskb, y);
}

// Round 30
// 87.270 us; speedup vs baseline: 1.0563x; 1.0174x over previous
//
#include <hip/hip_runtime.h>

typedef float    f32x4 __attribute__((ext_vector_type(4)));
typedef short    s16x8 __attribute__((ext_vector_type(8)));
typedef _Float16 f16x8 __attribute__((ext_vector_type(8)));
typedef _Float16 f16x4 __attribute__((ext_vector_type(4)));
typedef unsigned int   u32x4 __attribute__((ext_vector_type(4)));

// B=8, N=1024, F=1024, H=16, D=64

__device__ __forceinline__ unsigned short bf16rne(float f){
  unsigned u = __float_as_uint(f);
  return (unsigned short)((u + 0x7FFFu + ((u >> 16) & 1u)) >> 16);
}

// ---------------- fused prep: adjmask | xbf | prepw (grid-branched) -----------
__global__ __launch_bounds__(256) void prep_kernel(const int* __restrict__ adj,
    const float* __restrict__ x, const float* __restrict__ W,
    unsigned* __restrict__ maskb, unsigned short* __restrict__ xb,
    unsigned short* __restrict__ Wt)
{
  const int bid = blockIdx.x, tid = threadIdx.x;
  if (bid < 1024) {
    const int lane = tid & 63;
    int gw = (bid * 256 + tid) >> 6;
    for (int s = gw; s < 131072; s += 4096) {
      int a = adj[(size_t)s * 64 + lane];
      unsigned long long m = __ballot(a > 0);
      if (lane == 0) {
        maskb[s * 2]     = (unsigned)m;
        maskb[s * 2 + 1] = (unsigned)(m >> 32);
      }
    }
  } else if (bid < 5120) {
    int idx = ((bid - 1024) * 256 + tid) * 8;
    f32x4 v0 = *reinterpret_cast<const f32x4*>(&x[idx]);
    f32x4 v1 = *reinterpret_cast<const f32x4*>(&x[idx + 4]);
    u32x4 o;
    o[0] = (unsigned)bf16rne(v0[0]) | ((unsigned)bf16rne(v0[1]) << 16);
    o[1] = (unsigned)bf16rne(v0[2]) | ((unsigned)bf16rne(v0[3]) << 16);
    o[2] = (unsigned)bf16rne(v1[0]) | ((unsigned)bf16rne(v1[1]) << 16);
    o[3] = (unsigned)bf16rne(v1[2]) | ((unsigned)bf16rne(v1[3]) << 16);
    *reinterpret_cast<u32x4*>(&xb[idx]) = o;
  } else {
    __shared__ float t[16][17];
    int rel = bid - 5120;
    int f0 = (rel & 63) * 16, d0 = ((rel >> 6) & 3) * 16, hh = rel >> 8;
    const int tx = tid & 15, ty = tid >> 4;
    t[ty][tx] = W[(size_t)hh * 65536 + (size_t)(f0 + ty) * 64 + (d0 + tx)];
    __syncthreads();
    float v = t[tx][ty];  // = W[hh][f0+tx][d0+ty]
    size_t o = (size_t)(hh * 64 + d0 + ty) * 1024 + (f0 + tx);
    Wt[o] = bf16rne(v);
  }
}

// ---------------- Wh = xb @ Wt^T — 128x128, static dbuf, global_load_lds ------
#define GSTAGE(BUF, K0) { \
  _Pragma("unroll") \
  for (int r = 0; r < 2; ++r) { \
    int flat = r * 256 + tid; \
    int row = flat >> 2, o8 = (flat & 3) << 3; \
    __builtin_amdgcn_global_load_lds( \
        (const __attribute__((address_space(1))) unsigned*)&xb[(size_t)(m0 + row) * 1024 + (K0) + o8], \
        (__attribute__((address_space(3))) unsigned*)&Ah[BUF][(r * 256 + (wave << 6)) * 8], 16, 0, 0); \
    __builtin_amdgcn_global_load_lds( \
        (const __attribute__((address_space(1))) unsigned*)&Btg[(size_t)(n0 + row) * 1024 + (K0) + o8], \
        (__attribute__((address_space(3))) unsigned*)&Bh[BUF][(r * 256 + (wave << 6)) * 8], 16, 0, 0); \
  } }

#define GCOMP(BUF) { \
    s16x8 ah[4], bh[4]; \
    _Pragma("unroll") \
    for (int i = 0; i < 4; ++i) \
      ah[i] = *reinterpret_cast<const s16x8*>(&Ah[BUF][(wm + i * 16 + rA) * 32 + kg * 8]); \
    _Pragma("unroll") \
    for (int j = 0; j < 4; ++j) \
      bh[j] = *reinterpret_cast<const s16x8*>(&Bh[BUF][(wn + j * 16 + rA) * 32 + kg * 8]); \
    _Pragma("unroll") \
    for (int i = 0; i < 4; ++i) \
      _Pragma("unroll") \
      for (int j = 0; j < 4; ++j) \
        acc[i][j] = __builtin_amdgcn_mfma_f32_16x16x32_bf16(ah[i], bh[j], acc[i][j], 0, 0, 0); }

__global__ __launch_bounds__(256, 3) void gemm_kernel(const unsigned short* __restrict__ xb,
    const unsigned short* __restrict__ Btg,
    const float* __restrict__ a1, const float* __restrict__ a2,
    _Float16* __restrict__ WhT, float* __restrict__ f1, float* __restrict__ f2)
{
  __shared__ unsigned short Ah[2][128 * 32], Bh[2][128 * 32];
  const int tid  = threadIdx.x;
  const int lane = tid & 63, wave = tid >> 6;
  const int m0 = blockIdx.x * 128, n0 = blockIdx.y * 128;
  const int wm = (wave & 1) * 64, wn = (wave >> 1) * 64;
  const int rA = lane & 15, kg = lane >> 4;

  f32x4 acc[4][4] = {};

  GSTAGE(0, 0);
  __syncthreads();
  for (int k0 = 0; k0 < 1024; k0 += 64) {
    GSTAGE(1, k0 + 32);
    GCOMP(0);
    __syncthreads();
    if (k0 + 64 < 1024) { GSTAGE(0, k0 + 64); }
    GCOMP(1);
    __syncthreads();
  }

  // epilogue 1: WhT f16 [(bh*64+d)*1024 + n-within-batch]
#pragma unroll
  for (int i = 0; i < 4; ++i) {
    int gm0 = m0 + wm + i * 16 + kg * 4;  // 4 consecutive rows
#pragma unroll
    for (int j = 0; j < 4; ++j) {
      int gn = n0 + wn + j * 16 + rA;
      int bb = gm0 >> 10, nn = gm0 & 1023;
      int hh = gn >> 6,  dd = gn & 63;
      f16x4 hv;
#pragma unroll
      for (int jj = 0; jj < 4; ++jj) hv[jj] = (_Float16)acc[i][j][jj];
      *reinterpret_cast<f16x4*>(&WhT[((size_t)((bb * 16 + hh) * 64 + dd) << 10) + nn]) = hv;
    }
  }

  // epilogue 2: fused f1/f2 (this wave's 64 cols = one complete head)
  const int hw = (n0 + wn) >> 6;        // absolute head 0..15
  float a1v[4], a2v[4];
#pragma unroll
  for (int j = 0; j < 4; ++j) {
    int d = j * 16 + rA;
    a1v[j] = a1[hw * 64 + d];
    a2v[j] = a2[hw * 64 + d];
  }
#pragma unroll
  for (int i = 0; i < 4; ++i) {
#pragma unroll
    for (int jj = 0; jj < 4; ++jj) {
      float s1 = 0.f, s2 = 0.f;
#pragma unroll
      for (int j = 0; j < 4; ++j) {
        float v = acc[i][j][jj];
        s1 += v * a1v[j];
        s2 += v * a2v[j];
      }
#pragma unroll
      for (int off = 1; off < 16; off <<= 1) {
        s1 += __shfl_xor(s1, off);
        s2 += __shfl_xor(s2, off);
      }
      if (rA == 0) {
        int gm = m0 + wm + i * 16 + kg * 4 + jj;
        int bb = gm >> 10, nn = gm & 1023;
        size_t o = (size_t)(bb * 16 + hw) * 1024 + nn;
        f1[o] = s1;
        f2[o] = s2;
      }
    }
  }
}

// ---------------- PV: R29 math, static dbuf (cur-free codegen), XCD swizzle ---
#define PSTAGE(BUF, M0) { \
  _Pragma("unroll") \
  for (int r = 0; r < 2; ++r) { \
    int flat = r * 256 + tid; int d = flat >> 3; int o = (flat & 7) << 3; \
    *reinterpret_cast<u32x4*>(&Bsh[BUF][d * 72 + o]) = \
        *reinterpret_cast<const u32x4*>(&whtb[(size_t)d * 1024 + (M0) + o]); \
  } }

#define PVCOMP(BUF, M0, MWARR) { \
    f32x4 cd[2][4]; \
    _Pragma("unroll") \
    for (int ks = 0; ks < 2; ++ks) { \
      const int kc = (M0) + ks * 32 + kg * 8; \
      cd[ks][0] = *reinterpret_cast<const f32x4*>(&Cs[kc]); \
      cd[ks][1] = *reinterpret_cast<const f32x4*>(&Cs[kc + 4]); \
      cd[ks][2] = *reinterpret_cast<const f32x4*>(&Ds[kc]); \
      cd[ks][3] = *reinterpret_cast<const f32x4*>(&Ds[kc + 4]); \
    } \
    _Pragma("unroll") \
    for (int ks = 0; ks < 2; ++ks) { \
      f16x8 pa[2]; \
      _Pragma("unroll") \
      for (int t = 0; t < 2; ++t) { \
        unsigned mw = (&MWARR[t].x)[ks] >> (kg * 8); \
        float pv_[8]; \
        _Pragma("unroll") \
        for (int jj = 0; jj < 8; ++jj) { \
          float C = (jj < 4) ? cd[ks][0][jj] : cd[ks][1][jj - 4]; \
          float D = (jj < 4) ? cd[ks][2][jj] : cd[ks][3][jj - 4]; \
          pv_[jj] = fmaxf(At[t] * C, Bt[t] * D); \
        } \
        u32x4 pw; \
        pw[0] = __builtin_bit_cast(unsigned, __builtin_amdgcn_cvt_pkrtz(pv_[0], pv_[1])); \
        pw[1] = __builtin_bit_cast(unsigned, __builtin_amdgcn_cvt_pkrtz(pv_[2], pv_[3])); \
        pw[2] = __builtin_bit_cast(unsigned, __builtin_amdgcn_cvt_pkrtz(pv_[4], pv_[5])); \
        pw[3] = __builtin_bit_cast(unsigned, __builtin_amdgcn_cvt_pkrtz(pv_[6], pv_[7])); \
        unsigned long long mq0 = lutm[mw & 15u]; \
        unsigned long long mq1 = lutm[(mw >> 4) & 15u]; \
        pw[0] &= (unsigned)mq0;  pw[1] &= (unsigned)(mq0 >> 32); \
        pw[2] &= (unsigned)mq1;  pw[3] &= (unsigned)(mq1 >> 32); \
        pa[t] = __builtin_bit_cast(f16x8, pw); \
        dacc[t] = __builtin_amdgcn_mfma_f32_16x16x32_f16(pa[t], ones, dacc[t], 0, 0, 0); \
      } \
      _Pragma("unroll") \
      for (int j = 0; j < 4; ++j) { \
        f16x8 bf = *reinterpret_cast<const f16x8*>(&Bsh[BUF][(j * 16 + rA) * 72 + ks * 32 + kg * 8]); \
        acc[0][j] = __builtin_amdgcn_mfma_f32_16x16x32_f16(pa[0], bf, acc[0][j], 0, 0, 0); \
        acc[1][j] = __builtin_amdgcn_mfma_f32_16x16x32_f16(pa[1], bf, acc[1][j], 0, 0, 0); \
      } \
    } }

__global__ __launch_bounds__(256, 4) void pv_kernel(const _Float16* __restrict__ WhT,
    const float* __restrict__ f1, const float* __restrict__ f2,
    const unsigned* __restrict__ maskb, float* __restrict__ y)
{
  const int tid = threadIdx.x, lane = tid & 63, wave = tid >> 6;
  const int lin = blockIdx.x;
  const int bh = ((lin >> 6) << 3) + (lin & 7);   // bh&7 = lin&7 -> xcd locality
  const int rb = (lin >> 3) & 7;
  const int b = bh >> 4, h = bh & 15;
  const int n0 = rb * 128;
  const _Float16* whtb = WhT + ((size_t)bh << 16);  // 64*1024 per (b,h)

  __shared__ _Float16 Bsh[2][64 * 72];
  __shared__ float Cs[1024], Ds[1024];
  __shared__ float smx[4];
  __shared__ unsigned long long lutm[16];

  const float K = 1.44269504f;

  // phase 0: compute C=2^f2', D=2^0.2f2' (+ block max of f2'), lut
  float pmax;
  {
    f32x4 fv = *reinterpret_cast<const f32x4*>(&f2[(size_t)bh * 1024 + tid * 4]);
    f32x4 sv, cv, dv;
#pragma unroll
    for (int e = 0; e < 4; ++e) {
      sv[e] = fv[e] * K;
      cv[e] = __builtin_amdgcn_exp2f(sv[e]);
      dv[e] = __builtin_amdgcn_exp2f(0.2f * sv[e]);
    }
    *reinterpret_cast<f32x4*>(&Cs[tid * 4]) = cv;
    *reinterpret_cast<f32x4*>(&Ds[tid * 4]) = dv;
    pmax = fmaxf(fmaxf(sv[0], sv[1]), fmaxf(sv[2], sv[3]));
  }
#pragma unroll
  for (int off = 32; off; off >>= 1) pmax = fmaxf(pmax, __shfl_xor(pmax, off));
  if (lane == 0) smx[wave] = pmax;
  if (tid < 16) {
    unsigned lo = ((tid & 1) ? 0xFFFFu : 0u) | ((tid & 2) ? 0xFFFF0000u : 0u);
    unsigned hi = ((tid & 4) ? 0xFFFFu : 0u) | ((tid & 8) ? 0xFFFF0000u : 0u);
    lutm[tid] = ((unsigned long long)hi << 32) | lo;
  }
  __syncthreads();

  const float m2s = fmaxf(fmaxf(smx[0], smx[1]), fmaxf(smx[2], smx[3]));

  const int rA = lane & 15, kg = lane >> 4;
  const int wrow = wave * 32;
  f32x4 acc[2][4] = {};
  f32x4 dacc[2] = {};
  int   rloc[2];
  float At[2], Bt[2];
  const unsigned* mrow[2];
#pragma unroll
  for (int t = 0; t < 2; ++t) {
    rloc[t] = wrow + t * 16 + rA;
    float f1p = f1[(size_t)bh * 1024 + n0 + rloc[t]] * K;
    float sf = f1p + m2s;
    float Mp = fmaxf(sf, 0.2f * sf);
    At[t] = __builtin_amdgcn_exp2f(f1p - Mp);
    Bt[t] = __builtin_amdgcn_exp2f(0.2f * f1p - Mp);
    mrow[t] = maskb + ((size_t)(b << 10) + n0 + rloc[t]) * 32;
  }
  f16x8 ones;
#pragma unroll
  for (int e = 0; e < 8; ++e) ones[e] = (_Float16)1.0f;

  uint2 mwA[2], mwB[2];
  mwA[0] = *reinterpret_cast<const uint2*>(&mrow[0][0]);
  mwA[1] = *reinterpret_cast<const uint2*>(&mrow[1][0]);
  PSTAGE(0, 0);
  __syncthreads();

  for (int m0 = 0; m0 < 1024; m0 += 128) {
    // phase A: prefetch m0+64 -> buf 1; compute tile m0 from buf 0
    PSTAGE(1, m0 + 64);
    mwB[0] = *reinterpret_cast<const uint2*>(&mrow[0][(m0 + 64) >> 5]);
    mwB[1] = *reinterpret_cast<const uint2*>(&mrow[1][(m0 + 64) >> 5]);
    PVCOMP(0, m0, mwA);
    __syncthreads();
    // phase B: prefetch m0+128 -> buf 0; compute tile m0+64 from buf 1
    if (m0 + 128 < 1024) {
      PSTAGE(0, m0 + 128);
      mwA[0] = *reinterpret_cast<const uint2*>(&mrow[0][(m0 + 128) >> 5]);
      mwA[1] = *reinterpret_cast<const uint2*>(&mrow[1][(m0 + 128) >> 5]);
    }
    PVCOMP(1, m0 + 64, mwB);
    __syncthreads();
  }

  // epilogue: dacc[t] rows (t*16 + kg*4+jj) align with acc[t] rows
#pragma unroll
  for (int t = 0; t < 2; ++t) {
    f32x4 rd;
#pragma unroll
    for (int jj = 0; jj < 4; ++jj) rd[jj] = dacc[t][jj] > 0.f ? 1.0f / dacc[t][jj] : 0.f;
#pragma unroll
    for (int j = 0; j < 4; ++j) {
#pragma unroll
      for (int jj = 0; jj < 4; ++jj) {
        int row = wrow + t * 16 + kg * 4 + jj;
        int n = n0 + row, d = j * 16 + rA;
        y[(((size_t)b * 1024 + n) << 10) + h * 64 + d] = acc[t][j][jj] * rd[jj];
      }
    }
  }
}

extern "C" void kernel_launch(void* const* d_in, const int* in_sizes, int n_in,
                              void* d_out, int out_size, void* d_ws, size_t ws_size,
                              hipStream_t stream)
{
  const float* x  = (const float*)d_in[0];
  const int*   adj = (const int*)d_in[1];
  const float* W  = (const float*)d_in[2];
  const float* a1 = (const float*)d_in[3];
  const float* a2 = (const float*)d_in[4];
  float* y = (float*)d_out;

  char* ws = (char*)d_ws;
  unsigned short* Wt = (unsigned short*)(ws);                       // 2 MB
  unsigned*       maskb = (unsigned*)(ws + ((size_t)2 << 20));      // 1 MB
  float* f1   = (float*)(ws + ((size_t)3 << 20));                   // 512 KB
  float* f2   = (float*)(ws + ((size_t)3 << 20) + ((size_t)512 << 10));
  _Float16* WhT = (_Float16*)(ws + ((size_t)4 << 20));              // 16 MB
  unsigned short* xb = (unsigned short*)(ws + ((size_t)20 << 20));  // 16 MB

  prep_kernel<<<9216, 256, 0, stream>>>(adj, x, W, maskb, xb, Wt);
  gemm_kernel<<<dim3(64, 8), 256, 0, stream>>>(xb, Wt, a1, a2, WhT, f1, f2);
  pv_kernel<<<1024, 256, 0, stream>>>(WhT, f1, f2, maskb, y);
}